// Round 4
// baseline (523.032 us; speedup 1.0000x reference)
//
#include <hip/hip_runtime.h>

// Problem constants (from reference)
#define BATCH 64
#define KNEIGH 3
#define NPTS 8192
#define FIN 64
#define FOUT 64
#define DDIM (KNEIGH * FIN)            // 192 — contraction dim after reshape
#define SPLIT 32                       // blocks per batch in stage 1
#define PER_BATCH_F4 (KNEIGH * NPTS * FIN / 4)   // 393216 float4 per batch

// Stage 1: S[b][j][fin] = sum over rows r of batch b with r%3==j of x_row[fin]
// where r indexes the 24576 rows of 64 floats (k*8192+n), and the reference's
// reshape maps row r to kernel-slot j = r % 3 (== (2k+n) % 3).
__global__ __launch_bounds__(256) void lg_reduce_kernel(const float* __restrict__ x,
                                                        float* __restrict__ S) {
    const int t = threadIdx.x;
    const int b = blockIdx.x / SPLIT;
    const int s = blockIdx.x % SPLIT;

    const float4* __restrict__ xb =
        (const float4*)(x + (size_t)b * (KNEIGH * NPTS * FIN));

    float4 a0 = make_float4(0.f, 0.f, 0.f, 0.f);
    float4 a1 = a0, a2 = a0;

    // Grid-stride over this batch's float4s. stride = SPLIT*256 (multiple of 16),
    // so this thread's within-row f4 slot (idx & 15) is constant => fixed fin base.
    for (int idx = s * 256 + t; idx < PER_BATCH_F4; idx += SPLIT * 256) {
        float4 v = xb[idx];
        int j = (idx >> 4) % 3;   // row index r = idx/16 (16 float4 per 64-float row)
        // Branch-free 3-way bucket accumulate (lanes in a wave differ in j).
        float m0 = (j == 0) ? 1.f : 0.f;
        float m1 = (j == 1) ? 1.f : 0.f;
        float m2 = (j == 2) ? 1.f : 0.f;
        a0.x = fmaf(v.x, m0, a0.x); a0.y = fmaf(v.y, m0, a0.y);
        a0.z = fmaf(v.z, m0, a0.z); a0.w = fmaf(v.w, m0, a0.w);
        a1.x = fmaf(v.x, m1, a1.x); a1.y = fmaf(v.y, m1, a1.y);
        a1.z = fmaf(v.z, m1, a1.z); a1.w = fmaf(v.w, m1, a1.w);
        a2.x = fmaf(v.x, m2, a2.x); a2.y = fmaf(v.y, m2, a2.y);
        a2.z = fmaf(v.z, m2, a2.z); a2.w = fmaf(v.w, m2, a2.w);
    }

    // Block reduction: threads sharing (t & 15) hold the same fin range.
    __shared__ float4 red[3][256];   // 12 KB
    red[0][t] = a0; red[1][t] = a1; red[2][t] = a2;
    __syncthreads();
    for (int off = 128; off >= 16; off >>= 1) {
        if (t < off) {
            #pragma unroll
            for (int j = 0; j < 3; ++j) {
                float4 a = red[j][t], c = red[j][t + off];
                a.x += c.x; a.y += c.y; a.z += c.z; a.w += c.w;
                red[j][t] = a;
            }
        }
        __syncthreads();
    }
    // Threads 0..47: j = t/16, fin base = (t%16)*4 — one global atomicAdd per float.
    if (t < 48) {
        const int j = t >> 4;
        const int ff = t & 15;
        float4 v = red[j][ff];
        float* Sb = S + (size_t)b * DDIM + j * FIN + ff * 4;
        atomicAdd(Sb + 0, v.x);
        atomicAdd(Sb + 1, v.y);
        atomicAdd(Sb + 2, v.z);
        atomicAdd(Sb + 3, v.w);
    }
}

// Stage 2: out[b][f] = relu(bias[f] + sum_d S[b][d] * kw[d][f]),  d in [0,192)
__global__ __launch_bounds__(64) void lg_out_kernel(const float* __restrict__ S,
                                                    const float* __restrict__ kw,
                                                    const float* __restrict__ bias,
                                                    float* __restrict__ out) {
    const int b = blockIdx.x;
    const int f = threadIdx.x;   // 64 threads
    __shared__ float sl[DDIM];
    #pragma unroll
    for (int i = 0; i < 3; ++i) sl[i * 64 + f] = S[(size_t)b * DDIM + i * 64 + f];
    __syncthreads();
    float acc = bias[f];
    #pragma unroll
    for (int d = 0; d < DDIM; ++d) acc = fmaf(sl[d], kw[d * FOUT + f], acc);
    out[b * FOUT + f] = fmaxf(acc, 0.f);
}

extern "C" void kernel_launch(void* const* d_in, const int* in_sizes, int n_in,
                              void* d_out, int out_size, void* d_ws, size_t ws_size,
                              hipStream_t stream) {
    const float* x    = (const float*)d_in[0];   // (64,3,8192,64) f32
    const float* kern = (const float*)d_in[1];   // (3,64,64) f32
    const float* bias = (const float*)d_in[2];   // (64,) f32
    float* out = (float*)d_out;                  // (64,64) f32
    float* S   = (float*)d_ws;                   // (64,192) f32 accumulator

    // d_ws is poisoned with 0xAA before every call — zero the accumulator.
    hipMemsetAsync(d_ws, 0, BATCH * DDIM * sizeof(float), stream);

    lg_reduce_kernel<<<BATCH * SPLIT, 256, 0, stream>>>(x, S);
    lg_out_kernel<<<BATCH, 64, 0, stream>>>(S, kern, bias, out);
}